// Round 4
// baseline (2005.173 us; speedup 1.0000x reference)
//
#include <hip/hip_runtime.h>
#include <hip/hip_bf16.h>
#include <hip/hip_cooperative_groups.h>
#include <stdint.h>

// DecoderScannedRNN: T=256, B=64, D=1024. GRU scan with done-resets.
// Segment-depth decomposition + hoisted x-projection.
// NEW this round:
//  (a) k_xproj XCD map pins B per XCD (tn in {3x..3x+2}, 768 KB L2-resident);
//      A streams tm-major with trio reuse + L3 absorption. Round-3 map pinned
//      A and thrashed the 6 MB WiT through L2 -> 225 MB FETCH.
//  (b) ALL 32 phases fused into ONE cooperative kernel (grid 512 = 2/CU at
//      80 KB LDS), grid.sync() between non-empty phases. Replaces 32
//      stream-serialized launches (~10 us each; empty phases were pure cost).
//  (c) phase tiles use the same B-pinning XCD map (dblk pairs per XCD).
//  Fallback: if cooperative launch fails, per-phase normal launches (dosync=0).

#define T_STEPS 256
#define NB 64
#define DIM 1024
#define NPH 32

namespace cg = cooperative_groups;

typedef unsigned short u16;
typedef __attribute__((ext_vector_type(8))) short bf16x8;
typedef __attribute__((ext_vector_type(4))) float f32x4;

__device__ __forceinline__ float b2f(u16 u){ union{unsigned i; float f;} v; v.i=((unsigned)u)<<16; return v.f; }
__device__ __forceinline__ u16 f2b(float f){
  union { __hip_bfloat16 h; u16 u; } v; v.h = __float2bfloat16(f); return v.u;
}
__device__ __forceinline__ unsigned pk2(float lo, float hi){
  union { __hip_bfloat162 h; unsigned u; } v;
  v.h = __float22bfloat162_rn(make_float2(lo, hi));
  return v.u;
}
__device__ __forceinline__ float sigf(float x){ return 1.0f/(1.0f+__expf(-x)); }
__device__ __forceinline__ float tanh_f(float x){ float ax=fabsf(x); float e=__expf(-2.0f*ax); float t=(1.0f-e)/(1.0f+e); return copysignf(t,x); }

// Async global->LDS 16B: dest = wave-uniform lbase + lane*16B.
__device__ __forceinline__ void gl_lds16(const u16* g, u16* lbase, int lane){
#if __has_builtin(__builtin_amdgcn_global_load_lds)
  __builtin_amdgcn_global_load_lds(
      (const __attribute__((address_space(1))) unsigned int*)g,
      (__attribute__((address_space(3))) unsigned int*)lbase, 16, 0, 0);
#else
  *(uint4*)(lbase + lane*8) = *(const uint4*)g;
#endif
}

// Stage 8 elements (16B of bf16) into LDS from base+eoff (f32 or bf16 source).
__device__ __forceinline__ void stage16(const void* base, size_t eoff, int isf, u16* dst){
  if (isf){
    const float* f = (const float*)base + eoff;
    f32x4 a0 = *(const f32x4*)f;
    f32x4 a1 = *(const f32x4*)(f+4);
    uint4 w;
    w.x = pk2(a0[0],a0[1]); w.y = pk2(a0[2],a0[3]);
    w.z = pk2(a1[0],a1[1]); w.w = pk2(a1[2],a1[3]);
    *(uint4*)dst = w;
  } else {
    *(uint4*)dst = *(const uint4*)((const u16*)base + eoff);
  }
}

// dones mode: 0=int32, 3=f32, 2=bf16, 1=bytes.
__device__ __forceinline__ int get_mode(const int* d){
  return (!d[0]) ? 0 : ((!d[1]) ? 3 : ((!d[2]) ? 2 : 1));
}
__device__ __forceinline__ int get_done(const void* dn, int mode, int i){
  if (mode == 0) return ((const int*)dn)[i] != 0;
  if (mode == 3) return ((const unsigned*)dn)[i] != 0;
  if (mode == 2) return ((const u16*)dn)[i] != 0;
  return ((const unsigned char*)dn)[i] != 0;
}

__global__ void k_setup0(const void* dones, const void* ins, int* cnt, int* cur, int* dflag){
  int tid = threadIdx.x;
  if (tid < NPH){ cnt[tid]=0; cur[tid]=0; }
  if (tid < 4) dflag[tid]=0;
  __syncthreads();
  const unsigned* di = (const unsigned*)dones;
  int vInt=0, vF32=0, vB16=0;
  for (int i = tid; i < 4096; i += 256){
    unsigned v = di[i];
    if (v > 1u) vInt = 1;
    if (v != 0u && v != 0x3F800000u) vF32 = 1;
    unsigned h0 = v & 0xFFFFu, h1 = v >> 16;
    if ((h0 != 0u && h0 != 0x3F80u) || (h1 != 0u && h1 != 0x3F80u)) vB16 = 1;
  }
  if (vInt) atomicOr(&dflag[0], 1);
  if (vF32) atomicOr(&dflag[1], 1);
  if (vB16) atomicOr(&dflag[2], 1);
  const u16* iu = (const u16*)ins;
  int f = 0;
  for (int i = tid; i < 4096; i += 256){
    u16 u = iu[2*i];
    if (((u >> 7) & 0xFF) >= 160) f = 1;
  }
  if (f) atomicOr(&dflag[3], 1);
}

__global__ void k_assign(const void* dones, const int* dflag, int* s_of, int* cnt){
  __shared__ unsigned char sd[T_STEPS];
  int b = blockIdx.x, t = threadIdx.x;
  int mode = get_mode(dflag);
  sd[t] = (unsigned char)get_done(dones, mode, t*NB + b);
  __syncthreads();
  int tt = t;
  while (tt > 0 && !sd[tt]) --tt;
  int s = t - tt;
  if (s >= NPH) s = NPH-1;
  s_of[t*NB + b] = s;
  atomicAdd(&cnt[s], 1);
}

__global__ void k_scan(const int* cnt, int* basep, int* cur){
  if (threadIdx.x == 0){
    int a = 0;
    for (int i=0;i<NPH;++i){ basep[i]=a; a += cnt[i]; }
    basep[NPH] = a;
  }
  if (threadIdx.x < NPH) cur[threadIdx.x] = 0;
}

// Deterministic sorted fill (ballot prefix): rows of phase s in (t,b) order.
__global__ void k_fill(const void* dones, const int* dflag, const int* s_of,
                       const int* basep, int* row_tb, int* row_src){
  int s = blockIdx.x;
  __shared__ int runbase;
  __shared__ int wsum[4];
  int tid = threadIdx.x, lane = tid & 63, wave = tid >> 6;
  int mode = get_mode(dflag);
  if (tid == 0) runbase = basep[s];
  __syncthreads();
  for (int i0 = 0; i0 < T_STEPS*NB; i0 += 256){
    int i = i0 + tid;
    int match = (s_of[i] == s);
    unsigned long long mask = __ballot(match);
    if (lane == 0) wsum[wave] = __popcll(mask);
    __syncthreads();
    int off = runbase;
    for (int w = 0; w < wave; ++w) off += wsum[w];
    int total = wsum[0] + wsum[1] + wsum[2] + wsum[3];
    if (match){
      int pos = off + __popcll(mask & ((1ull << lane) - 1ull));
      row_tb[pos] = i;
      int t = i >> 6, b = i & 63;
      int code;
      if (s > 0) code = (t-1)*NB + b;
      else if (get_done(dones, mode, i)) code = i | 0x40000000;
      else code = b | 0x20000000;
      row_src[pos] = code;
    }
    __syncthreads();
    if (tid == 0) runbase += total;
  }
}

// W [1024][3072] -> WT [3072][1024] bf16 (convert if f32).
__global__ void k_transpose(const void* __restrict__ W, u16* __restrict__ WT, const int* dflag){
  __shared__ u16 ts[64][65];
  int k0 = blockIdx.x*64, n0 = blockIdx.y*64, tid = threadIdx.x;
  int isf = dflag[3];
  for (int i = tid; i < 4096; i += 256){
    int r=i>>6, c=i&63; int idx=(k0+r)*3072 + n0 + c;
    ts[r][c] = isf ? f2b(((const float*)W)[idx]) : ((const u16*)W)[idx];
  }
  __syncthreads();
  for (int i = tid; i < 4096; i += 256){
    int r=i>>6, c=i&63;
    WT[(n0+r)*DIM + k0 + c] = ts[c][r];
  }
}

__global__ void k_bias(const void* bi, const void* bhn, const int* dflag,
                       u16* bi_b, u16* bhn_b){
  int isf = dflag[3];
  int i = blockIdx.x*256 + threadIdx.x;
  if (i < 3072) bi_b[i] = isf ? f2b(((const float*)bi)[i]) : ((const u16*)bi)[i];
  else { int j=i-3072; bhn_b[j] = isf ? f2b(((const float*)bhn)[j]) : ((const u16*)bhn)[j]; }
}

__device__ __forceinline__ void hsrc(int code, const void* outv, const void* hiddens,
                                     const void* initc, const void** hb, size_t* ho){
  if (code & 0x40000000){ *hb = hiddens; *ho = (size_t)(code & 0x0FFFFFFF)*DIM; }
  else if (code & 0x20000000){ *hb = initc; *ho = (size_t)(code & 0x0FFFFFFF)*DIM; }
  else { *hb = outv; *ho = (size_t)NB*DIM + (size_t)code*DIM; }
}

// ---------------------------------------------------------------------------
// Hoisted x-projection: Xp[16384][3072] = cvt(ins @ Wi). 128x128 tiles, BK=64,
// single-barrier dbuf pipeline. XCD map pins B: XCD x owns tn {3x..3x+2}
// (768 KB, L2-resident); A streams tm-major with trio reuse (L3 absorbs).
// ---------------------------------------------------------------------------
__global__ __launch_bounds__(256, 2) void k_xproj(
    const void* __restrict__ ins, const u16* __restrict__ WiT,
    const int* __restrict__ dflag, u16* __restrict__ xp)
{
  __shared__ u16 As[2][128*64];
  __shared__ u16 Bs[2][128*64];
  int isf = dflag[3];
  int tid=threadIdx.x, wave=tid>>6, lane=tid&63, quad=lane>>4, l16=lane&15;
  int wm=wave&1, wn=wave>>1;
  int srow = wave*8 + (lane>>3), c8=(lane&7)*8;
  int swzc = c8 ^ ((srow&7)<<3);
  int rsw = (l16&7)<<3;
  int idx = blockIdx.x >> 3;
  int tn = (blockIdx.x & 7)*3 + (idx % 3);
  int tm = idx / 3;
  f32x4 acc[4][4] = {};
  unsigned aoff[4], boff[4];
  #pragma unroll
  for (int p=0;p<4;++p){
    aoff[p] = (unsigned)(tm*128 + p*32 + srow)*DIM + c8;
    boff[p] = (unsigned)(tn*128 + p*32 + srow)*DIM + swzc;
  }
  // prologue
  #pragma unroll
  for (int p=0;p<4;++p) gl_lds16(WiT + boff[p], &Bs[0][(p*32+wave*8)*64], lane);
  #pragma unroll
  for (int p=0;p<4;++p) stage16(ins, aoff[p], isf, &As[0][(p*32+srow)*64 + swzc]);
  __syncthreads();
  int cur = 0;
  #pragma unroll 1
  for (int ko=64; ko<1024; ko+=64){
    #pragma unroll
    for (int p=0;p<4;++p) gl_lds16(WiT + boff[p] + ko, &Bs[cur^1][(p*32+wave*8)*64], lane);
    f32x4 pr0[4], pr1[4];
    #pragma unroll
    for (int p=0;p<4;++p){
      if (isf){ const float* f=(const float*)ins + aoff[p] + ko; pr0[p]=*(const f32x4*)f; pr1[p]=*(const f32x4*)(f+4); }
      else pr0[p]=*(const f32x4*)((const u16*)ins + aoff[p] + ko);
    }
    #pragma unroll
    for (int kk=0;kk<64;kk+=32){
      int rc = (kk + quad*8) ^ rsw;
      bf16x8 af[4], bfv[4];
      #pragma unroll
      for (int mi=0;mi<4;++mi) af[mi]  = *(const bf16x8*)&As[cur][(wm*64+mi*16+l16)*64 + rc];
      #pragma unroll
      for (int ni=0;ni<4;++ni) bfv[ni] = *(const bf16x8*)&Bs[cur][(wn*64+ni*16+l16)*64 + rc];
      #pragma unroll
      for (int mi=0;mi<4;++mi)
        #pragma unroll
        for (int ni=0;ni<4;++ni)
          acc[mi][ni] = __builtin_amdgcn_mfma_f32_16x16x32_bf16(af[mi],bfv[ni],acc[mi][ni],0,0,0);
    }
    #pragma unroll
    for (int p=0;p<4;++p){
      uint4 w;
      if (isf){ w.x=pk2(pr0[p][0],pr0[p][1]); w.y=pk2(pr0[p][2],pr0[p][3]);
                w.z=pk2(pr1[p][0],pr1[p][1]); w.w=pk2(pr1[p][2],pr1[p][3]); }
      else { union{f32x4 f; uint4 u;} cv; cv.f=pr0[p]; w=cv.u; }
      *(uint4*)&As[cur^1][(p*32+srow)*64 + swzc] = w;
    }
    __syncthreads();
    cur ^= 1;
  }
  #pragma unroll
  for (int kk=0;kk<64;kk+=32){
    int rc = (kk + quad*8) ^ rsw;
    bf16x8 af[4], bfv[4];
    #pragma unroll
    for (int mi=0;mi<4;++mi) af[mi]  = *(const bf16x8*)&As[cur][(wm*64+mi*16+l16)*64 + rc];
    #pragma unroll
    for (int ni=0;ni<4;++ni) bfv[ni] = *(const bf16x8*)&Bs[cur][(wn*64+ni*16+l16)*64 + rc];
    #pragma unroll
    for (int mi=0;mi<4;++mi)
      #pragma unroll
      for (int ni=0;ni<4;++ni)
        acc[mi][ni] = __builtin_amdgcn_mfma_f32_16x16x32_bf16(af[mi],bfv[ni],acc[mi][ni],0,0,0);
  }
  #pragma unroll
  for (int mi=0;mi<4;++mi){
    int row = tm*128 + wm*64 + mi*16 + quad*4;
    #pragma unroll
    for (int ni=0;ni<4;++ni){
      int colB = tn*128 + wn*64 + ni*16 + l16;
      u16* op = xp + (size_t)row*3072 + colB;
      #pragma unroll
      for (int j=0;j<4;++j)
        op[(size_t)j*3072] = f2b(acc[mi][ni][j]);
    }
  }
}

// ---- fat tile: 128 rows x 64 d-cols (192 gate rows), BK=64, dbuf ----
#define FAT_MFMA(BUF, NGRP)                                                    \
        _Pragma("unroll")                                                      \
        for (int kk=0;kk<64;kk+=32){                                           \
          int rc = (kk + quad*8) ^ rsw;                                        \
          bf16x8 af[4];                                                        \
          _Pragma("unroll")                                                    \
          for (int mi=0;mi<4;++mi)                                             \
            af[mi] = *(const bf16x8*)&As[BUF][(wm*64+mi*16+l16)*64 + rc];      \
          _Pragma("unroll")                                                    \
          for (int g=0;g<3;++g){                                               \
            int grp = (g==2) ? (NGRP) : g;                                     \
            _Pragma("unroll")                                                  \
            for (int ni=0;ni<2;++ni){                                          \
              bf16x8 bfr = *(const bf16x8*)&Bs[BUF][(g*64+wn*32+ni*16+l16)*64 + rc]; \
              _Pragma("unroll")                                                \
              for (int mi=0;mi<4;++mi)                                         \
                acc[grp][mi][ni] = __builtin_amdgcn_mfma_f32_16x16x32_bf16(af[mi],bfr,acc[grp][mi][ni],0,0,0); \
            }                                                                  \
          }                                                                    \
        }

#define FAT_PANEL(BASEARR, OFFARR, WTP, NGRP)                                  \
    {                                                                          \
      __syncthreads();                                                         \
      _Pragma("unroll")                                                        \
      for (int p=0;p<6;++p)                                                    \
        gl_lds16(WTP + boffB[p], &Bs[0][(p*32+wave*8)*64], lane);              \
      _Pragma("unroll")                                                        \
      for (int p=0;p<4;++p)                                                    \
        stage16(BASEARR[p], OFFARR[p], isf, &As[0][(p*32+srow)*64 + swzc]);    \
      __syncthreads();                                                         \
      int cur = 0;                                                             \
      _Pragma("unroll 1")                                                      \
      for (int ko=64; ko<1024; ko+=64){                                        \
        _Pragma("unroll")                                                      \
        for (int p=0;p<6;++p)                                                  \
          gl_lds16(WTP + boffB[p] + ko, &Bs[cur^1][(p*32+wave*8)*64], lane);   \
        f32x4 pr0[4], pr1[4];                                                  \
        _Pragma("unroll")                                                      \
        for (int p=0;p<4;++p){                                                 \
          if (isf){ const float* f=(const float*)BASEARR[p]+OFFARR[p]+ko;      \
            pr0[p]=*(const f32x4*)f; pr1[p]=*(const f32x4*)(f+4); }            \
          else pr0[p]=*(const f32x4*)((const u16*)BASEARR[p]+OFFARR[p]+ko);    \
        }                                                                      \
        FAT_MFMA(cur, NGRP)                                                    \
        _Pragma("unroll")                                                      \
        for (int p=0;p<4;++p){                                                 \
          uint4 w;                                                             \
          if (isf){ w.x=pk2(pr0[p][0],pr0[p][1]); w.y=pk2(pr0[p][2],pr0[p][3]);\
                    w.z=pk2(pr1[p][0],pr1[p][1]); w.w=pk2(pr1[p][2],pr1[p][3]);}\
          else { union{f32x4 f; uint4 u;} cv; cv.f=pr0[p]; w=cv.u; }           \
          *(uint4*)&As[cur^1][(p*32+srow)*64 + swzc] = w;                      \
        }                                                                      \
        __syncthreads();                                                       \
        cur ^= 1;                                                              \
      }                                                                        \
      FAT_MFMA(cur, NGRP)                                                      \
    }

// ---------------------------------------------------------------------------
// Unified phase kernel: handles phases [s0,s1). Cooperative launch (dosync=1)
// runs all phases with grid.sync() between non-empty ones; fallback launches
// one phase at a time with dosync=0. Fat 128x64 geometry for every phase
// (padding absorbs tiny counts). XCD map: XCD owns dblk pair (B 768 KB in L2).
// ---------------------------------------------------------------------------
template<bool HOIST>
__global__ __launch_bounds__(256, 2) void k_phases(
    int s0, int s1, int dosync,
    const int* __restrict__ cnt, const int* __restrict__ basep,
    const int* __restrict__ row_tb, const int* __restrict__ row_src,
    const void* __restrict__ ins, const void* __restrict__ hiddens,
    const void* __restrict__ initc, const u16* __restrict__ WiT,
    const u16* __restrict__ WhT, const u16* __restrict__ bi_b,
    const u16* __restrict__ bhn_b, const int* __restrict__ dflag,
    const u16* __restrict__ xp, void* __restrict__ outv)
{
  __shared__ u16 As[2][128*64];
  __shared__ u16 Bs[2][192*64];
  int isf = dflag[3];
  int tid=threadIdx.x, wave=tid>>6, lane=tid&63, quad=lane>>4, l16=lane&15;
  int wm=wave&1, wn=wave>>1;
  int srow = wave*8 + (lane>>3), c8=(lane&7)*8;
  int swzc = c8 ^ ((srow&7)<<3);
  int rsw = (l16&7)<<3;
  constexpr int NG = HOIST ? 3 : 4;

  for (int s = s0; s < s1; ++s){
    int count = cnt[s];
    if (count <= 0) continue;
    int base = basep[s];
    int mtiles = (count + 127) >> 7;
    int ntot = mtiles << 4;                 // 16 dblks of 64 d-cols
    for (int raw = blockIdx.x; raw < ntot; raw += gridDim.x){
      int idx2 = raw >> 3;
      int dblk = ((raw & 7) << 1) | (idx2 & 1);  // XCD owns a dblk pair
      int tm = idx2 >> 1;
      int d0 = dblk*64;
      unsigned xoff[4], hoff[4];
      const void* hbv[4];
      const void* xbv[4];
      #pragma unroll
      for (int p=0;p<4;++p){
        int lr = tm*128 + p*32 + srow;
        int idx = base + ((lr < count) ? lr : 0);
        int tb = row_tb[idx], code = row_src[idx];
        xoff[p] = (unsigned)tb*DIM + c8;
        xbv[p] = ins;
        size_t ho; const void* hb;
        hsrc(code, outv, hiddens, initc, &hb, &ho);
        hbv[p] = hb; hoff[p] = (unsigned)ho + c8;
      }
      // B rows: R = p*32+srow in [0,192): gate g = p>>1, d-col r = (p&1)*32+srow
      int boffB[6];
      #pragma unroll
      for (int p=0;p<6;++p)
        boffB[p] = ((p>>1)*DIM + d0 + (p&1)*32 + srow)*DIM + swzc;
      f32x4 acc[NG][4][2] = {};

      if constexpr (!HOIST){
        FAT_PANEL(xbv, xoff, WiT, 2)
      }
      FAT_PANEL(hbv, hoff, WhT, (NG-1))

      // ---- fused GRU epilogue ----
      int col0 = d0 + wn*32;
      float brv[2], bzv[2], bnv[2], bhv[2];
      #pragma unroll
      for (int ni=0;ni<2;++ni){
        int c = col0 + ni*16 + l16;
        brv[ni]=b2f(bi_b[c]); bzv[ni]=b2f(bi_b[1024+c]);
        bnv[ni]=b2f(bi_b[2048+c]); bhv[ni]=b2f(bhn_b[c]);
      }
      #pragma unroll
      for (int mi=0;mi<4;++mi){
        int lrow0 = tm*128 + wm*64 + mi*16 + quad*4;
        #pragma unroll
        for (int j=0;j<4;++j){
          int lrow = lrow0 + j;
          if (lrow >= count) continue;
          int idx = base + lrow;
          int tb = row_tb[idx], code = row_src[idx];
          size_t ho; const void* hb;
          hsrc(code, outv, hiddens, initc, &hb, &ho);
          #pragma unroll
          for (int ni=0;ni<2;++ni){
            int c = col0 + ni*16 + l16;
            float hpv = isf ? ((const float*)hb)[ho + c] : b2f(((const u16*)hb)[ho + c]);
            float xr = 0.f, xz = 0.f, xn = 0.f;
            if constexpr (HOIST){
              const u16* xrow = xp + (size_t)tb*3072 + c;
              xr = b2f(xrow[0]); xz = b2f(xrow[1024]); xn = b2f(xrow[2048]);
            }
            float r = sigf(brv[ni] + xr + acc[0][mi][ni][j]);
            float z = sigf(bzv[ni] + xz + acc[1][mi][ni][j]);
            float nx = HOIST ? xn : acc[2][mi][ni][j];
            float n = tanh_f(bnv[ni] + nx + r*(acc[NG-1][mi][ni][j] + bhv[ni]));
            float hnew = (1.0f - z)*n + z*hpv;
            size_t yo = (size_t)NB*DIM + (size_t)tb*DIM + c;
            if (isf) ((float*)outv)[yo] = hnew;
            else     ((u16*)outv)[yo] = f2b(hnew);
          }
        }
      }
    }
    if (dosync){
      __threadfence();
      cg::this_grid().sync();
    }
  }
}

__global__ void k_final(const int* dflag, void* out){
  int isf = dflag[3];
  size_t i = (size_t)(blockIdx.x*256 + threadIdx.x)*4;
  size_t src = (size_t)NB*DIM + (size_t)(T_STEPS-1)*NB*DIM;
  if (isf){
    float* o = (float*)out;
    *(f32x4*)(o + i) = *(const f32x4*)(o + src + i);
  } else {
    u16* o = (u16*)out;
    *(uint2*)(o + i) = *(const uint2*)(o + src + i);
  }
}

extern "C" void kernel_launch(void* const* d_in, const int* in_sizes, int n_in,
                              void* d_out, int out_size, void* d_ws, size_t ws_size,
                              hipStream_t stream){
  const void* ins = d_in[0];
  const void* hid = d_in[1];
  const void* dn  = d_in[2];
  const void* ini = d_in[3];
  const void* Wi  = d_in[4];
  const void* Wh  = d_in[5];
  const void* bi  = d_in[6];
  const void* bhn = d_in[7];

  char* ws = (char*)d_ws;
  int* dflag  = (int*)(ws + 0);
  int* cnt    = (int*)(ws + 256);
  int* basep  = (int*)(ws + 512);
  int* cur    = (int*)(ws + 1024);
  int* s_of   = (int*)(ws + 4096);          // 64 KB
  int* row_tb = (int*)(ws + 69632);         // 64 KB
  int* row_src= (int*)(ws + 135168);        // 64 KB
  u16* bi_b   = (u16*)(ws + 200704);        // 6 KB
  u16* bhn_b  = (u16*)(ws + 208896);        // 2 KB
  u16* WiT    = (u16*)(ws + 262144);        // 6 MB
  u16* WhT    = (u16*)(ws + 6553600);       // 6 MB (end 12845056)
  u16* xp     = (u16*)(ws + 12845056);      // 96 MB bf16 Xp (if ws allows)

  const int hoist = (ws_size >= 113508352ull) ? 1 : 0;

  k_setup0<<<1,256,0,stream>>>(dn, ins, cnt, cur, dflag);
  k_assign<<<NB,T_STEPS,0,stream>>>(dn, dflag, s_of, cnt);
  k_scan<<<1,64,0,stream>>>(cnt, basep, cur);
  k_fill<<<NPH,256,0,stream>>>(dn, dflag, s_of, basep, row_tb, row_src);
  k_transpose<<<dim3(16,48),256,0,stream>>>(Wi, WiT, dflag);
  k_transpose<<<dim3(16,48),256,0,stream>>>(Wh, WhT, dflag);
  k_bias<<<16,256,0,stream>>>(bi, bhn, dflag, bi_b, bhn_b);

  if (hoist) k_xproj<<<3072,256,0,stream>>>(ins, WiT, dflag, xp);

  const void* kfn = hoist ? reinterpret_cast<const void*>(&k_phases<true>)
                          : reinterpret_cast<const void*>(&k_phases<false>);
  int mb = 0;
  if (hipOccupancyMaxActiveBlocksPerMultiprocessor(&mb, kfn, 256, 0) != hipSuccess || mb < 1)
    mb = 2;
  int grid = mb * 256;
  if (grid > 512) grid = 512;

  int s0 = 0, s1 = NPH, dosync = 1;
  void* params[] = { &s0, &s1, &dosync, &cnt, &basep, &row_tb, &row_src,
                     &ins, &hid, &ini, &WiT, &WhT, &bi_b, &bhn_b,
                     &dflag, &xp, &d_out };
  hipError_t ce = hipLaunchCooperativeKernel(kfn, dim3(grid), dim3(256),
                                             params, 0, stream);
  if (ce != hipSuccess){
    // Fallback: per-phase normal launches (no grid sync needed across launches).
    for (int s = 0; s < NPH; ++s){
      if (hoist)
        k_phases<true><<<512,256,0,stream>>>(s, s+1, 0, cnt, basep, row_tb, row_src,
                                             ins, hid, ini, WiT, WhT, bi_b, bhn_b,
                                             dflag, xp, d_out);
      else
        k_phases<false><<<512,256,0,stream>>>(s, s+1, 0, cnt, basep, row_tb, row_src,
                                              ins, hid, ini, WiT, WhT, bi_b, bhn_b,
                                              dflag, xp, d_out);
    }
  }
  k_final<<<64,256,0,stream>>>(dflag, d_out);
}

// Round 5
// 1134.486 us; speedup vs baseline: 1.7675x; 1.7675x over previous
//
#include <hip/hip_runtime.h>
#include <hip/hip_bf16.h>
#include <stdint.h>

// DecoderScannedRNN: T=256, B=64, D=1024. GRU scan with done-resets.
// Segment-depth decomposition + hoisted x-projection.
// NEW this round (post-mortem of failed cooperative fusion):
//  (a) REVERT cooperative grid.sync fusion (measured: ~2 ms, grid.sync on
//      8 non-coherent XCDs is ~50-75 us/sync + L2 poisoning). Back to
//      stream-ordered per-phase launches (graph replay makes them ~3-5 us).
//  (b) k_xproj keeps round-4 B-pinned XCD map: XCD x owns tn {3x..3x+2}
//      (768 KB WiT slice L2-resident); A streams, L3 absorbs re-reads.
//  (c) phase_fat gets the same dblk-pinned map (round-3 xcdswz was tm-pinned
//      and cycled all 6 MB of WhT through each 4 MB L2 -> FETCH blowup).

#define T_STEPS 256
#define NB 64
#define DIM 1024
#define NPH 32

typedef unsigned short u16;
typedef __attribute__((ext_vector_type(8))) short bf16x8;
typedef __attribute__((ext_vector_type(4))) float f32x4;

__device__ __forceinline__ float b2f(u16 u){ union{unsigned i; float f;} v; v.i=((unsigned)u)<<16; return v.f; }
__device__ __forceinline__ u16 f2b(float f){
  union { __hip_bfloat16 h; u16 u; } v; v.h = __float2bfloat16(f); return v.u;
}
__device__ __forceinline__ unsigned pk2(float lo, float hi){
  union { __hip_bfloat162 h; unsigned u; } v;
  v.h = __float22bfloat162_rn(make_float2(lo, hi));
  return v.u;
}
__device__ __forceinline__ float sigf(float x){ return 1.0f/(1.0f+__expf(-x)); }
__device__ __forceinline__ float tanh_f(float x){ float ax=fabsf(x); float e=__expf(-2.0f*ax); float t=(1.0f-e)/(1.0f+e); return copysignf(t,x); }

// Async global->LDS 16B: dest = wave-uniform lbase + lane*16B.
__device__ __forceinline__ void gl_lds16(const u16* g, u16* lbase, int lane){
#if __has_builtin(__builtin_amdgcn_global_load_lds)
  __builtin_amdgcn_global_load_lds(
      (const __attribute__((address_space(1))) unsigned int*)g,
      (__attribute__((address_space(3))) unsigned int*)lbase, 16, 0, 0);
#else
  *(uint4*)(lbase + lane*8) = *(const uint4*)g;
#endif
}

// Stage 8 elements (16B of bf16) into LDS from base+eoff (f32 or bf16 source).
__device__ __forceinline__ void stage16(const void* base, size_t eoff, int isf, u16* dst){
  if (isf){
    const float* f = (const float*)base + eoff;
    f32x4 a0 = *(const f32x4*)f;
    f32x4 a1 = *(const f32x4*)(f+4);
    uint4 w;
    w.x = pk2(a0[0],a0[1]); w.y = pk2(a0[2],a0[3]);
    w.z = pk2(a1[0],a1[1]); w.w = pk2(a1[2],a1[3]);
    *(uint4*)dst = w;
  } else {
    *(uint4*)dst = *(const uint4*)((const u16*)base + eoff);
  }
}

// dones mode: 0=int32, 3=f32, 2=bf16, 1=bytes.
__device__ __forceinline__ int get_mode(const int* d){
  return (!d[0]) ? 0 : ((!d[1]) ? 3 : ((!d[2]) ? 2 : 1));
}
__device__ __forceinline__ int get_done(const void* dn, int mode, int i){
  if (mode == 0) return ((const int*)dn)[i] != 0;
  if (mode == 3) return ((const unsigned*)dn)[i] != 0;
  if (mode == 2) return ((const u16*)dn)[i] != 0;
  return ((const unsigned char*)dn)[i] != 0;
}

__global__ void k_setup0(const void* dones, const void* ins, int* cnt, int* cur, int* dflag){
  int tid = threadIdx.x;
  if (tid < NPH){ cnt[tid]=0; cur[tid]=0; }
  if (tid < 4) dflag[tid]=0;
  __syncthreads();
  const unsigned* di = (const unsigned*)dones;
  int vInt=0, vF32=0, vB16=0;
  for (int i = tid; i < 4096; i += 256){
    unsigned v = di[i];
    if (v > 1u) vInt = 1;
    if (v != 0u && v != 0x3F800000u) vF32 = 1;
    unsigned h0 = v & 0xFFFFu, h1 = v >> 16;
    if ((h0 != 0u && h0 != 0x3F80u) || (h1 != 0u && h1 != 0x3F80u)) vB16 = 1;
  }
  if (vInt) atomicOr(&dflag[0], 1);
  if (vF32) atomicOr(&dflag[1], 1);
  if (vB16) atomicOr(&dflag[2], 1);
  const u16* iu = (const u16*)ins;
  int f = 0;
  for (int i = tid; i < 4096; i += 256){
    u16 u = iu[2*i];
    if (((u >> 7) & 0xFF) >= 160) f = 1;
  }
  if (f) atomicOr(&dflag[3], 1);
}

__global__ void k_assign(const void* dones, const int* dflag, int* s_of, int* cnt){
  __shared__ unsigned char sd[T_STEPS];
  int b = blockIdx.x, t = threadIdx.x;
  int mode = get_mode(dflag);
  sd[t] = (unsigned char)get_done(dones, mode, t*NB + b);
  __syncthreads();
  int tt = t;
  while (tt > 0 && !sd[tt]) --tt;
  int s = t - tt;
  if (s >= NPH) s = NPH-1;
  s_of[t*NB + b] = s;
  atomicAdd(&cnt[s], 1);
}

__global__ void k_scan(const int* cnt, int* basep, int* cur){
  if (threadIdx.x == 0){
    int a = 0;
    for (int i=0;i<NPH;++i){ basep[i]=a; a += cnt[i]; }
    basep[NPH] = a;
  }
  if (threadIdx.x < NPH) cur[threadIdx.x] = 0;
}

// Deterministic sorted fill (ballot prefix): rows of phase s in (t,b) order.
__global__ void k_fill(const void* dones, const int* dflag, const int* s_of,
                       const int* basep, int* row_tb, int* row_src){
  int s = blockIdx.x;
  __shared__ int runbase;
  __shared__ int wsum[4];
  int tid = threadIdx.x, lane = tid & 63, wave = tid >> 6;
  int mode = get_mode(dflag);
  if (tid == 0) runbase = basep[s];
  __syncthreads();
  for (int i0 = 0; i0 < T_STEPS*NB; i0 += 256){
    int i = i0 + tid;
    int match = (s_of[i] == s);
    unsigned long long mask = __ballot(match);
    if (lane == 0) wsum[wave] = __popcll(mask);
    __syncthreads();
    int off = runbase;
    for (int w = 0; w < wave; ++w) off += wsum[w];
    int total = wsum[0] + wsum[1] + wsum[2] + wsum[3];
    if (match){
      int pos = off + __popcll(mask & ((1ull << lane) - 1ull));
      row_tb[pos] = i;
      int t = i >> 6, b = i & 63;
      int code;
      if (s > 0) code = (t-1)*NB + b;
      else if (get_done(dones, mode, i)) code = i | 0x40000000;
      else code = b | 0x20000000;
      row_src[pos] = code;
    }
    __syncthreads();
    if (tid == 0) runbase += total;
  }
}

// W [1024][3072] -> WT [3072][1024] bf16 (convert if f32).
__global__ void k_transpose(const void* __restrict__ W, u16* __restrict__ WT, const int* dflag){
  __shared__ u16 ts[64][65];
  int k0 = blockIdx.x*64, n0 = blockIdx.y*64, tid = threadIdx.x;
  int isf = dflag[3];
  for (int i = tid; i < 4096; i += 256){
    int r=i>>6, c=i&63; int idx=(k0+r)*3072 + n0 + c;
    ts[r][c] = isf ? f2b(((const float*)W)[idx]) : ((const u16*)W)[idx];
  }
  __syncthreads();
  for (int i = tid; i < 4096; i += 256){
    int r=i>>6, c=i&63;
    WT[(n0+r)*DIM + k0 + c] = ts[c][r];
  }
}

__global__ void k_bias(const void* bi, const void* bhn, const int* dflag,
                       u16* bi_b, u16* bhn_b){
  int isf = dflag[3];
  int i = blockIdx.x*256 + threadIdx.x;
  if (i < 3072) bi_b[i] = isf ? f2b(((const float*)bi)[i]) : ((const u16*)bi)[i];
  else { int j=i-3072; bhn_b[j] = isf ? f2b(((const float*)bhn)[j]) : ((const u16*)bhn)[j]; }
}

__device__ __forceinline__ void hsrc(int code, const void* outv, const void* hiddens,
                                     const void* initc, const void** hb, size_t* ho){
  if (code & 0x40000000){ *hb = hiddens; *ho = (size_t)(code & 0x0FFFFFFF)*DIM; }
  else if (code & 0x20000000){ *hb = initc; *ho = (size_t)(code & 0x0FFFFFFF)*DIM; }
  else { *hb = outv; *ho = (size_t)NB*DIM + (size_t)code*DIM; }
}

// ---------------------------------------------------------------------------
// Hoisted x-projection: Xp[16384][3072] = cvt(ins @ Wi). 128x128 tiles, BK=64,
// single-barrier dbuf pipeline. XCD map pins B: XCD x owns tn {3x..3x+2}
// (768 KB, L2-resident); A streams tm-major (L3 absorbs re-reads).
// ---------------------------------------------------------------------------
__global__ __launch_bounds__(256, 2) void k_xproj(
    const void* __restrict__ ins, const u16* __restrict__ WiT,
    const int* __restrict__ dflag, u16* __restrict__ xp)
{
  __shared__ u16 As[2][128*64];
  __shared__ u16 Bs[2][128*64];
  int isf = dflag[3];
  int tid=threadIdx.x, wave=tid>>6, lane=tid&63, quad=lane>>4, l16=lane&15;
  int wm=wave&1, wn=wave>>1;
  int srow = wave*8 + (lane>>3), c8=(lane&7)*8;
  int swzc = c8 ^ ((srow&7)<<3);
  int rsw = (l16&7)<<3;
  int idx = blockIdx.x >> 3;
  int tn = (blockIdx.x & 7)*3 + (idx % 3);
  int tm = idx / 3;
  f32x4 acc[4][4] = {};
  unsigned aoff[4], boff[4];
  #pragma unroll
  for (int p=0;p<4;++p){
    aoff[p] = (unsigned)(tm*128 + p*32 + srow)*DIM + c8;
    boff[p] = (unsigned)(tn*128 + p*32 + srow)*DIM + swzc;
  }
  // prologue
  #pragma unroll
  for (int p=0;p<4;++p) gl_lds16(WiT + boff[p], &Bs[0][(p*32+wave*8)*64], lane);
  #pragma unroll
  for (int p=0;p<4;++p) stage16(ins, aoff[p], isf, &As[0][(p*32+srow)*64 + swzc]);
  __syncthreads();
  int cur = 0;
  #pragma unroll 1
  for (int ko=64; ko<1024; ko+=64){
    #pragma unroll
    for (int p=0;p<4;++p) gl_lds16(WiT + boff[p] + ko, &Bs[cur^1][(p*32+wave*8)*64], lane);
    f32x4 pr0[4], pr1[4];
    #pragma unroll
    for (int p=0;p<4;++p){
      if (isf){ const float* f=(const float*)ins + aoff[p] + ko; pr0[p]=*(const f32x4*)f; pr1[p]=*(const f32x4*)(f+4); }
      else pr0[p]=*(const f32x4*)((const u16*)ins + aoff[p] + ko);
    }
    #pragma unroll
    for (int kk=0;kk<64;kk+=32){
      int rc = (kk + quad*8) ^ rsw;
      bf16x8 af[4], bfv[4];
      #pragma unroll
      for (int mi=0;mi<4;++mi) af[mi]  = *(const bf16x8*)&As[cur][(wm*64+mi*16+l16)*64 + rc];
      #pragma unroll
      for (int ni=0;ni<4;++ni) bfv[ni] = *(const bf16x8*)&Bs[cur][(wn*64+ni*16+l16)*64 + rc];
      #pragma unroll
      for (int mi=0;mi<4;++mi)
        #pragma unroll
        for (int ni=0;ni<4;++ni)
          acc[mi][ni] = __builtin_amdgcn_mfma_f32_16x16x32_bf16(af[mi],bfv[ni],acc[mi][ni],0,0,0);
    }
    #pragma unroll
    for (int p=0;p<4;++p){
      uint4 w;
      if (isf){ w.x=pk2(pr0[p][0],pr0[p][1]); w.y=pk2(pr0[p][2],pr0[p][3]);
                w.z=pk2(pr1[p][0],pr1[p][1]); w.w=pk2(pr1[p][2],pr1[p][3]); }
      else { union{f32x4 f; uint4 u;} cv; cv.f=pr0[p]; w=cv.u; }
      *(uint4*)&As[cur^1][(p*32+srow)*64 + swzc] = w;
    }
    __syncthreads();
    cur ^= 1;
  }
  #pragma unroll
  for (int kk=0;kk<64;kk+=32){
    int rc = (kk + quad*8) ^ rsw;
    bf16x8 af[4], bfv[4];
    #pragma unroll
    for (int mi=0;mi<4;++mi) af[mi]  = *(const bf16x8*)&As[cur][(wm*64+mi*16+l16)*64 + rc];
    #pragma unroll
    for (int ni=0;ni<4;++ni) bfv[ni] = *(const bf16x8*)&Bs[cur][(wn*64+ni*16+l16)*64 + rc];
    #pragma unroll
    for (int mi=0;mi<4;++mi)
      #pragma unroll
      for (int ni=0;ni<4;++ni)
        acc[mi][ni] = __builtin_amdgcn_mfma_f32_16x16x32_bf16(af[mi],bfv[ni],acc[mi][ni],0,0,0);
  }
  #pragma unroll
  for (int mi=0;mi<4;++mi){
    int row = tm*128 + wm*64 + mi*16 + quad*4;
    #pragma unroll
    for (int ni=0;ni<4;++ni){
      int colB = tn*128 + wn*64 + ni*16 + l16;
      u16* op = xp + (size_t)row*3072 + colB;
      #pragma unroll
      for (int j=0;j<4;++j)
        op[(size_t)j*3072] = f2b(acc[mi][ni][j]);
    }
  }
}

// ---- fat tile: 128 rows x 64 d-cols (192 gate rows), BK=64, dbuf ----
#define FAT_MFMA(BUF, NGRP)                                                    \
        _Pragma("unroll")                                                      \
        for (int kk=0;kk<64;kk+=32){                                           \
          int rc = (kk + quad*8) ^ rsw;                                        \
          bf16x8 af[4];                                                        \
          _Pragma("unroll")                                                    \
          for (int mi=0;mi<4;++mi)                                             \
            af[mi] = *(const bf16x8*)&As[BUF][(wm*64+mi*16+l16)*64 + rc];      \
          _Pragma("unroll")                                                    \
          for (int g=0;g<3;++g){                                               \
            int grp = (g==2) ? (NGRP) : g;                                     \
            _Pragma("unroll")                                                  \
            for (int ni=0;ni<2;++ni){                                          \
              bf16x8 bfr = *(const bf16x8*)&Bs[BUF][(g*64+wn*32+ni*16+l16)*64 + rc]; \
              _Pragma("unroll")                                                \
              for (int mi=0;mi<4;++mi)                                         \
                acc[grp][mi][ni] = __builtin_amdgcn_mfma_f32_16x16x32_bf16(af[mi],bfr,acc[grp][mi][ni],0,0,0); \
            }                                                                  \
          }                                                                    \
        }

#define FAT_PANEL(BASEARR, OFFARR, WTP, NGRP)                                  \
    {                                                                          \
      __syncthreads();                                                         \
      _Pragma("unroll")                                                        \
      for (int p=0;p<6;++p)                                                    \
        gl_lds16(WTP + boffB[p], &Bs[0][(p*32+wave*8)*64], lane);              \
      _Pragma("unroll")                                                        \
      for (int p=0;p<4;++p)                                                    \
        stage16(BASEARR[p], OFFARR[p], isf, &As[0][(p*32+srow)*64 + swzc]);    \
      __syncthreads();                                                         \
      int cur = 0;                                                             \
      _Pragma("unroll 1")                                                      \
      for (int ko=64; ko<1024; ko+=64){                                        \
        _Pragma("unroll")                                                      \
        for (int p=0;p<6;++p)                                                  \
          gl_lds16(WTP + boffB[p] + ko, &Bs[cur^1][(p*32+wave*8)*64], lane);   \
        f32x4 pr0[4], pr1[4];                                                  \
        _Pragma("unroll")                                                      \
        for (int p=0;p<4;++p){                                                 \
          if (isf){ const float* f=(const float*)BASEARR[p]+OFFARR[p]+ko;      \
            pr0[p]=*(const f32x4*)f; pr1[p]=*(const f32x4*)(f+4); }            \
          else pr0[p]=*(const f32x4*)((const u16*)BASEARR[p]+OFFARR[p]+ko);    \
        }                                                                      \
        FAT_MFMA(cur, NGRP)                                                    \
        _Pragma("unroll")                                                      \
        for (int p=0;p<4;++p){                                                 \
          uint4 w;                                                             \
          if (isf){ w.x=pk2(pr0[p][0],pr0[p][1]); w.y=pk2(pr0[p][2],pr0[p][3]);\
                    w.z=pk2(pr1[p][0],pr1[p][1]); w.w=pk2(pr1[p][2],pr1[p][3]);}\
          else { union{f32x4 f; uint4 u;} cv; cv.f=pr0[p]; w=cv.u; }           \
          *(uint4*)&As[cur^1][(p*32+srow)*64 + swzc] = w;                      \
        }                                                                      \
        __syncthreads();                                                       \
        cur ^= 1;                                                              \
      }                                                                        \
      FAT_MFMA(cur, NGRP)                                                      \
    }

template<bool HOIST>
__global__ __launch_bounds__(256, 2) void phase_fat(
    int s, const int* __restrict__ pcnt, const int* __restrict__ pbase,
    const int* __restrict__ row_tb, const int* __restrict__ row_src,
    const void* __restrict__ ins, const void* __restrict__ hiddens,
    const void* __restrict__ initc, const u16* __restrict__ WiT,
    const u16* __restrict__ WhT, const u16* __restrict__ bi_b,
    const u16* __restrict__ bhn_b, const int* __restrict__ dflag,
    const u16* __restrict__ xp, void* __restrict__ outv)
{
  int count = pcnt[s];
  if (count <= 0) return;
  int isf = dflag[3];
  int base = pbase[s];
  int mtiles = (count + 127) >> 7;
  int ntot = mtiles << 4;                     // 16 dblks of 64 d-cols
  __shared__ u16 As[2][128*64];
  __shared__ u16 Bs[2][192*64];
  int tid=threadIdx.x, wave=tid>>6, lane=tid&63, quad=lane>>4, l16=lane&15;
  int wm=wave&1, wn=wave>>1;
  int srow = wave*8 + (lane>>3), c8=(lane&7)*8;
  int swzc = c8 ^ ((srow&7)<<3);
  int rsw = (l16&7)<<3;
  constexpr int NG = HOIST ? 3 : 4;

  for (int raw = blockIdx.x; raw < ntot; raw += gridDim.x){
    // dblk-pinned XCD map: XCD (raw&7) owns dblk pair {2x,2x+1};
    // WhT slice 2*384 KB stays L2-resident across all tm on that XCD.
    int idx2 = raw >> 3;
    int dblk = ((raw & 7) << 1) | (idx2 & 1);
    int tm = idx2 >> 1;
    int d0 = dblk*64;
    unsigned xoff[4], hoff[4];
    const void* hbv[4];
    const void* xbv[4];
    #pragma unroll
    for (int p=0;p<4;++p){
      int lr = tm*128 + p*32 + srow;
      int idx = base + ((lr < count) ? lr : 0);
      int tb = row_tb[idx], code = row_src[idx];
      xoff[p] = (unsigned)tb*DIM + c8;
      xbv[p] = ins;
      size_t ho; const void* hb;
      hsrc(code, outv, hiddens, initc, &hb, &ho);
      hbv[p] = hb; hoff[p] = (unsigned)ho + c8;
    }
    // B rows: R = p*32+srow in [0,192): gate g = p>>1, d-col r = (p&1)*32+srow
    int boffB[6];
    #pragma unroll
    for (int p=0;p<6;++p)
      boffB[p] = ((p>>1)*DIM + d0 + (p&1)*32 + srow)*DIM + swzc;
    f32x4 acc[NG][4][2] = {};

    if constexpr (!HOIST){
      FAT_PANEL(xbv, xoff, WiT, 2)
    }
    FAT_PANEL(hbv, hoff, WhT, (NG-1))

    // ---- fused GRU epilogue ----
    int col0 = d0 + wn*32;
    float brv[2], bzv[2], bnv[2], bhv[2];
    #pragma unroll
    for (int ni=0;ni<2;++ni){
      int c = col0 + ni*16 + l16;
      brv[ni]=b2f(bi_b[c]); bzv[ni]=b2f(bi_b[1024+c]);
      bnv[ni]=b2f(bi_b[2048+c]); bhv[ni]=b2f(bhn_b[c]);
    }
    #pragma unroll
    for (int mi=0;mi<4;++mi){
      int lrow0 = tm*128 + wm*64 + mi*16 + quad*4;
      #pragma unroll
      for (int j=0;j<4;++j){
        int lrow = lrow0 + j;
        if (lrow >= count) continue;
        int idx = base + lrow;
        int tb = row_tb[idx], code = row_src[idx];
        size_t ho; const void* hb;
        hsrc(code, outv, hiddens, initc, &hb, &ho);
        #pragma unroll
        for (int ni=0;ni<2;++ni){
          int c = col0 + ni*16 + l16;
          float hpv = isf ? ((const float*)hb)[ho + c] : b2f(((const u16*)hb)[ho + c]);
          float xr = 0.f, xz = 0.f, xn = 0.f;
          if constexpr (HOIST){
            const u16* xrow = xp + (size_t)tb*3072 + c;
            xr = b2f(xrow[0]); xz = b2f(xrow[1024]); xn = b2f(xrow[2048]);
          }
          float r = sigf(brv[ni] + xr + acc[0][mi][ni][j]);
          float z = sigf(bzv[ni] + xz + acc[1][mi][ni][j]);
          float nx = HOIST ? xn : acc[2][mi][ni][j];
          float n = tanh_f(bnv[ni] + nx + r*(acc[NG-1][mi][ni][j] + bhv[ni]));
          float hnew = (1.0f - z)*n + z*hpv;
          size_t yo = (size_t)NB*DIM + (size_t)tb*DIM + c;
          if (isf) ((float*)outv)[yo] = hnew;
          else     ((u16*)outv)[yo] = f2b(hnew);
        }
      }
    }
  }
}

// ---- thin tile: 64 rows x 16 d-cols (48 gate rows), BK=64, dbuf ----
#define THIN_MFMA(BUF, NGRP)                                                   \
      _Pragma("unroll")                                                        \
      for (int kk=0;kk<64;kk+=32){                                             \
        int rc = (kk + quad*8) ^ rsw;                                          \
        bf16x8 af = *(const bf16x8*)&As[BUF][(wave*16+l16)*64 + rc];           \
        _Pragma("unroll")                                                      \
        for (int g=0;g<3;++g){                                                 \
          bf16x8 bfr = *(const bf16x8*)&Bs[BUF][(g*16+l16)*64 + rc];           \
          int grp = (g==2) ? (NGRP) : g;                                       \
          acc[grp] = __builtin_amdgcn_mfma_f32_16x16x32_bf16(af,bfr,acc[grp],0,0,0); \
        }                                                                      \
      }

#define THIN_PANEL(BASEARR, OFFARR, WTP, NGRP)                                 \
    {                                                                          \
      __syncthreads();                                                         \
      gl_lds16(WTP + boffA, &Bs[0][(wave*8)*64], lane);                        \
      if (wave < 2) gl_lds16(WTP + boffC, &Bs[0][(32+wave*8)*64], lane);       \
      stage16(BASEARR[0], OFFARR[0], isf, &As[0][srow*64 + swzc]);             \
      stage16(BASEARR[1], OFFARR[1], isf, &As[0][(32+srow)*64 + swzc]);        \
      __syncthreads();                                                         \
      int cur = 0;                                                             \
      _Pragma("unroll 1")                                                      \
      for (int ko=64; ko<1024; ko+=64){                                        \
        gl_lds16(WTP + boffA + ko, &Bs[cur^1][(wave*8)*64], lane);             \
        if (wave < 2) gl_lds16(WTP + boffC + ko, &Bs[cur^1][(32+wave*8)*64], lane); \
        f32x4 pr0[2], pr1[2];                                                  \
        _Pragma("unroll")                                                      \
        for (int p=0;p<2;++p){                                                 \
          if (isf){ const float* f=(const float*)BASEARR[p]+OFFARR[p]+ko;      \
            pr0[p]=*(const f32x4*)f; pr1[p]=*(const f32x4*)(f+4); }            \
          else pr0[p]=*(const f32x4*)((const u16*)BASEARR[p]+OFFARR[p]+ko);    \
        }                                                                      \
        THIN_MFMA(cur, NGRP)                                                   \
        _Pragma("unroll")                                                      \
        for (int p=0;p<2;++p){                                                 \
          uint4 w;                                                             \
          if (isf){ w.x=pk2(pr0[p][0],pr0[p][1]); w.y=pk2(pr0[p][2],pr0[p][3]);\
                    w.z=pk2(pr1[p][0],pr1[p][1]); w.w=pk2(pr1[p][2],pr1[p][3]);}\
          else { union{f32x4 f; uint4 u;} cv; cv.f=pr0[p]; w=cv.u; }           \
          *(uint4*)&As[cur^1][(p*32+srow)*64 + swzc] = w;                      \
        }                                                                      \
        __syncthreads();                                                       \
        cur ^= 1;                                                              \
      }                                                                        \
      THIN_MFMA(cur, NGRP)                                                     \
    }

template<bool HOIST>
__global__ __launch_bounds__(256, 4) void phase_thin(
    int s, const int* __restrict__ pcnt, const int* __restrict__ pbase,
    const int* __restrict__ row_tb, const int* __restrict__ row_src,
    const void* __restrict__ ins, const void* __restrict__ hiddens,
    const void* __restrict__ initc, const u16* __restrict__ WiT,
    const u16* __restrict__ WhT, const u16* __restrict__ bi_b,
    const u16* __restrict__ bhn_b, const int* __restrict__ dflag,
    const u16* __restrict__ xp, void* __restrict__ outv)
{
  int count = pcnt[s];
  if (count <= 0) return;
  int isf = dflag[3];
  int base = pbase[s];
  int mtiles = (count + 63) >> 6;
  int ntot = mtiles << 6;
  __shared__ u16 As[2][64*64];
  __shared__ u16 Bs[2][48*64];
  int tid=threadIdx.x, wave=tid>>6, lane=tid&63, quad=lane>>4, l16=lane&15;
  int srow = wave*8 + (lane>>3), c8=(lane&7)*8;
  int swzc = c8 ^ ((srow&7)<<3);
  int rsw = (l16&7)<<3;
  constexpr int NG = HOIST ? 3 : 4;

  for (int tile = blockIdx.x; tile < ntot; tile += gridDim.x){
    int tm = tile >> 6, dblk = tile & 63, d0 = dblk*16;
    unsigned xoff[2], hoff[2];
    const void* hbv[2];
    const void* xbv[2];
    #pragma unroll
    for (int p=0;p<2;++p){
      int lr = tm*64 + p*32 + srow;
      int idx = base + ((lr < count) ? lr : 0);
      int tb = row_tb[idx], code = row_src[idx];
      xoff[p] = (unsigned)tb*DIM + c8;
      xbv[p] = ins;
      size_t ho; const void* hb;
      hsrc(code, outv, hiddens, initc, &hb, &ho);
      hbv[p] = hb; hoff[p] = (unsigned)ho + c8;
    }
    int boffA = ((srow>>4)*DIM + d0 + (srow&15))*DIM + swzc;   // gates 0,1 (rows 0..31)
    int boffC = (2*DIM + d0 + srow)*DIM + swzc;                // gate 2 (rows 32..47, wave<2)
    f32x4 acc[NG] = {};

    if constexpr (!HOIST){
      THIN_PANEL(xbv, xoff, WiT, 2)
    }
    THIN_PANEL(hbv, hoff, WhT, (HOIST ? 2 : 3))

    int col = d0 + l16;
    float br = b2f(bi_b[col]), bz = b2f(bi_b[1024+col]);
    float bn = b2f(bi_b[2048+col]), bh = b2f(bhn_b[col]);
    int lrow0 = tm*64 + wave*16 + quad*4;
    #pragma unroll
    for (int j=0;j<4;++j){
      int lrow = lrow0 + j;
      if (lrow >= count) continue;
      int idx = base + lrow;
      int tb = row_tb[idx], code = row_src[idx];
      size_t ho; const void* hb;
      hsrc(code, outv, hiddens, initc, &hb, &ho);
      float hpv = isf ? ((const float*)hb)[ho + col] : b2f(((const u16*)hb)[ho + col]);
      float xr = 0.f, xz = 0.f, xn = 0.f;
      if constexpr (HOIST){
        const u16* xrow = xp + (size_t)tb*3072 + col;
        xr = b2f(xrow[0]); xz = b2f(xrow[1024]); xn = b2f(xrow[2048]);
      }
      float r = sigf(br + xr + acc[0][j]);
      float z = sigf(bz + xz + acc[1][j]);
      float nx = HOIST ? xn : acc[2][j];
      float n = tanh_f(bn + nx + r*(acc[NG-1][j] + bh));
      float hnew = (1.0f - z)*n + z*hpv;
      size_t yo = (size_t)NB*DIM + (size_t)tb*DIM + col;
      if (isf) ((float*)outv)[yo] = hnew;
      else     ((u16*)outv)[yo] = f2b(hnew);
    }
  }
}

__global__ void k_final(const int* dflag, void* out){
  int isf = dflag[3];
  size_t i = (size_t)(blockIdx.x*256 + threadIdx.x)*4;
  size_t src = (size_t)NB*DIM + (size_t)(T_STEPS-1)*NB*DIM;
  if (isf){
    float* o = (float*)out;
    *(f32x4*)(o + i) = *(const f32x4*)(o + src + i);
  } else {
    u16* o = (u16*)out;
    *(uint2*)(o + i) = *(const uint2*)(o + src + i);
  }
}

extern "C" void kernel_launch(void* const* d_in, const int* in_sizes, int n_in,
                              void* d_out, int out_size, void* d_ws, size_t ws_size,
                              hipStream_t stream){
  const void* ins = d_in[0];
  const void* hid = d_in[1];
  const void* dn  = d_in[2];
  const void* ini = d_in[3];
  const void* Wi  = d_in[4];
  const void* Wh  = d_in[5];
  const void* bi  = d_in[6];
  const void* bhn = d_in[7];

  char* ws = (char*)d_ws;
  int* dflag  = (int*)(ws + 0);
  int* cnt    = (int*)(ws + 256);
  int* basep  = (int*)(ws + 512);
  int* cur    = (int*)(ws + 1024);
  int* s_of   = (int*)(ws + 4096);          // 64 KB
  int* row_tb = (int*)(ws + 69632);         // 64 KB
  int* row_src= (int*)(ws + 135168);        // 64 KB
  u16* bi_b   = (u16*)(ws + 200704);        // 6 KB
  u16* bhn_b  = (u16*)(ws + 208896);        // 2 KB
  u16* WiT    = (u16*)(ws + 262144);        // 6 MB
  u16* WhT    = (u16*)(ws + 6553600);       // 6 MB (end 12845056)
  u16* xp     = (u16*)(ws + 12845056);      // 96 MB bf16 Xp (if ws allows)

  const int hoist = (ws_size >= 113508352ull) ? 1 : 0;

  k_setup0<<<1,256,0,stream>>>(dn, ins, cnt, cur, dflag);
  k_assign<<<NB,T_STEPS,0,stream>>>(dn, dflag, s_of, cnt);
  k_scan<<<1,64,0,stream>>>(cnt, basep, cur);
  k_fill<<<NPH,256,0,stream>>>(dn, dflag, s_of, basep, row_tb, row_src);
  k_transpose<<<dim3(16,48),256,0,stream>>>(Wi, WiT, dflag);
  k_transpose<<<dim3(16,48),256,0,stream>>>(Wh, WhT, dflag);
  k_bias<<<16,256,0,stream>>>(bi, bhn, dflag, bi_b, bhn_b);

  if (hoist){
    k_xproj<<<3072,256,0,stream>>>(ins, WiT, dflag, xp);
    for (int s=0;s<6;++s)
      phase_fat<true><<<1024,256,0,stream>>>(s, cnt, basep, row_tb, row_src, ins, hid, ini,
                                             WiT, WhT, bi_b, bhn_b, dflag, xp, d_out);
    for (int s=6;s<NPH;++s)
      phase_thin<true><<<128,256,0,stream>>>(s, cnt, basep, row_tb, row_src, ins, hid, ini,
                                             WiT, WhT, bi_b, bhn_b, dflag, xp, d_out);
  } else {
    for (int s=0;s<6;++s)
      phase_fat<false><<<1024,256,0,stream>>>(s, cnt, basep, row_tb, row_src, ins, hid, ini,
                                              WiT, WhT, bi_b, bhn_b, dflag, xp, d_out);
    for (int s=6;s<NPH;++s)
      phase_thin<false><<<128,256,0,stream>>>(s, cnt, basep, row_tb, row_src, ins, hid, ini,
                                              WiT, WhT, bi_b, bhn_b, dflag, xp, d_out);
  }
  k_final<<<64,256,0,stream>>>(dflag, d_out);
}

// Round 6
// 979.782 us; speedup vs baseline: 2.0466x; 1.1579x over previous
//
#include <hip/hip_runtime.h>
#include <hip/hip_bf16.h>
#include <stdint.h>

// DecoderScannedRNN: T=256, B=64, D=1024. GRU scan with done-resets.
// Segment-depth decomposition + hoisted x-projection.
// NEW this round:
//  (a) counted-vmcnt barriers (T3/T4): replace __syncthreads() in GEMM ko-loops
//      with asm "s_waitcnt vmcnt(N_A) lgkmcnt(0); s_barrier". A-register
//      prefetch for ko+64 is issued AFTER the ds_write and stays in flight
//      ACROSS the barrier (cover ~1 full iter vs MFMA-only before). B
//      global_load_lds ops are older -> fully drained by vmcnt(N_A).
//  (b) GEMM bodies templated on ISF (f32 vs bf16 input) so the vmcnt
//      immediate is exact (f32: 8 A-loads, bf16: 4; thin 4/2).
//  (c) thin grid 128 -> 256.

#define T_STEPS 256
#define NB 64
#define DIM 1024
#define NPH 32

typedef unsigned short u16;
typedef __attribute__((ext_vector_type(8))) short bf16x8;
typedef __attribute__((ext_vector_type(4))) float f32x4;

// barrier with counted vmcnt: drains all but the N newest vmem ops (the A
// prefetch), flushes LDS writes, then s_barrier. "memory" clobber pins order.
#define BAR_N(N) asm volatile("s_waitcnt vmcnt(" #N ") lgkmcnt(0)\n\ts_barrier" ::: "memory")

__device__ __forceinline__ float b2f(u16 u){ union{unsigned i; float f;} v; v.i=((unsigned)u)<<16; return v.f; }
__device__ __forceinline__ u16 f2b(float f){
  union { __hip_bfloat16 h; u16 u; } v; v.h = __float2bfloat16(f); return v.u;
}
__device__ __forceinline__ unsigned pk2(float lo, float hi){
  union { __hip_bfloat162 h; unsigned u; } v;
  v.h = __float22bfloat162_rn(make_float2(lo, hi));
  return v.u;
}
__device__ __forceinline__ float sigf(float x){ return 1.0f/(1.0f+__expf(-x)); }
__device__ __forceinline__ float tanh_f(float x){ float ax=fabsf(x); float e=__expf(-2.0f*ax); float t=(1.0f-e)/(1.0f+e); return copysignf(t,x); }

__device__ __forceinline__ void gl_lds16(const u16* g, u16* lbase, int lane){
#if __has_builtin(__builtin_amdgcn_global_load_lds)
  __builtin_amdgcn_global_load_lds(
      (const __attribute__((address_space(1))) unsigned int*)g,
      (__attribute__((address_space(3))) unsigned int*)lbase, 16, 0, 0);
#else
  *(uint4*)(lbase + lane*8) = *(const uint4*)g;
#endif
}

// Stage 8 elements (16B of bf16) into LDS from base+eoff (f32 or bf16 source).
__device__ __forceinline__ void stage16(const void* base, size_t eoff, int isf, u16* dst){
  if (isf){
    const float* f = (const float*)base + eoff;
    f32x4 a0 = *(const f32x4*)f;
    f32x4 a1 = *(const f32x4*)(f+4);
    uint4 w;
    w.x = pk2(a0[0],a0[1]); w.y = pk2(a0[2],a0[3]);
    w.z = pk2(a1[0],a1[1]); w.w = pk2(a1[2],a1[3]);
    *(uint4*)dst = w;
  } else {
    *(uint4*)dst = *(const uint4*)((const u16*)base + eoff);
  }
}

// dones mode: 0=int32, 3=f32, 2=bf16, 1=bytes.
__device__ __forceinline__ int get_mode(const int* d){
  return (!d[0]) ? 0 : ((!d[1]) ? 3 : ((!d[2]) ? 2 : 1));
}
__device__ __forceinline__ int get_done(const void* dn, int mode, int i){
  if (mode == 0) return ((const int*)dn)[i] != 0;
  if (mode == 3) return ((const unsigned*)dn)[i] != 0;
  if (mode == 2) return ((const u16*)dn)[i] != 0;
  return ((const unsigned char*)dn)[i] != 0;
}

__global__ void k_setup0(const void* dones, const void* ins, int* cnt, int* cur, int* dflag){
  int tid = threadIdx.x;
  if (tid < NPH){ cnt[tid]=0; cur[tid]=0; }
  if (tid < 4) dflag[tid]=0;
  __syncthreads();
  const unsigned* di = (const unsigned*)dones;
  int vInt=0, vF32=0, vB16=0;
  for (int i = tid; i < 4096; i += 256){
    unsigned v = di[i];
    if (v > 1u) vInt = 1;
    if (v != 0u && v != 0x3F800000u) vF32 = 1;
    unsigned h0 = v & 0xFFFFu, h1 = v >> 16;
    if ((h0 != 0u && h0 != 0x3F80u) || (h1 != 0u && h1 != 0x3F80u)) vB16 = 1;
  }
  if (vInt) atomicOr(&dflag[0], 1);
  if (vF32) atomicOr(&dflag[1], 1);
  if (vB16) atomicOr(&dflag[2], 1);
  const u16* iu = (const u16*)ins;
  int f = 0;
  for (int i = tid; i < 4096; i += 256){
    u16 u = iu[2*i];
    if (((u >> 7) & 0xFF) >= 160) f = 1;
  }
  if (f) atomicOr(&dflag[3], 1);
}

__global__ void k_assign(const void* dones, const int* dflag, int* s_of, int* cnt){
  __shared__ unsigned char sd[T_STEPS];
  int b = blockIdx.x, t = threadIdx.x;
  int mode = get_mode(dflag);
  sd[t] = (unsigned char)get_done(dones, mode, t*NB + b);
  __syncthreads();
  int tt = t;
  while (tt > 0 && !sd[tt]) --tt;
  int s = t - tt;
  if (s >= NPH) s = NPH-1;
  s_of[t*NB + b] = s;
  atomicAdd(&cnt[s], 1);
}

__global__ void k_scan(const int* cnt, int* basep, int* cur){
  if (threadIdx.x == 0){
    int a = 0;
    for (int i=0;i<NPH;++i){ basep[i]=a; a += cnt[i]; }
    basep[NPH] = a;
  }
  if (threadIdx.x < NPH) cur[threadIdx.x] = 0;
}

// Deterministic sorted fill (ballot prefix): rows of phase s in (t,b) order.
__global__ void k_fill(const void* dones, const int* dflag, const int* s_of,
                       const int* basep, int* row_tb, int* row_src){
  int s = blockIdx.x;
  __shared__ int runbase;
  __shared__ int wsum[4];
  int tid = threadIdx.x, lane = tid & 63, wave = tid >> 6;
  int mode = get_mode(dflag);
  if (tid == 0) runbase = basep[s];
  __syncthreads();
  for (int i0 = 0; i0 < T_STEPS*NB; i0 += 256){
    int i = i0 + tid;
    int match = (s_of[i] == s);
    unsigned long long mask = __ballot(match);
    if (lane == 0) wsum[wave] = __popcll(mask);
    __syncthreads();
    int off = runbase;
    for (int w = 0; w < wave; ++w) off += wsum[w];
    int total = wsum[0] + wsum[1] + wsum[2] + wsum[3];
    if (match){
      int pos = off + __popcll(mask & ((1ull << lane) - 1ull));
      row_tb[pos] = i;
      int t = i >> 6, b = i & 63;
      int code;
      if (s > 0) code = (t-1)*NB + b;
      else if (get_done(dones, mode, i)) code = i | 0x40000000;
      else code = b | 0x20000000;
      row_src[pos] = code;
    }
    __syncthreads();
    if (tid == 0) runbase += total;
  }
}

// W [1024][3072] -> WT [3072][1024] bf16 (convert if f32).
__global__ void k_transpose(const void* __restrict__ W, u16* __restrict__ WT, const int* dflag){
  __shared__ u16 ts[64][65];
  int k0 = blockIdx.x*64, n0 = blockIdx.y*64, tid = threadIdx.x;
  int isf = dflag[3];
  for (int i = tid; i < 4096; i += 256){
    int r=i>>6, c=i&63; int idx=(k0+r)*3072 + n0 + c;
    ts[r][c] = isf ? f2b(((const float*)W)[idx]) : ((const u16*)W)[idx];
  }
  __syncthreads();
  for (int i = tid; i < 4096; i += 256){
    int r=i>>6, c=i&63;
    WT[(n0+r)*DIM + k0 + c] = ts[c][r];
  }
}

__global__ void k_bias(const void* bi, const void* bhn, const int* dflag,
                       u16* bi_b, u16* bhn_b){
  int isf = dflag[3];
  int i = blockIdx.x*256 + threadIdx.x;
  if (i < 3072) bi_b[i] = isf ? f2b(((const float*)bi)[i]) : ((const u16*)bi)[i];
  else { int j=i-3072; bhn_b[j] = isf ? f2b(((const float*)bhn)[j]) : ((const u16*)bhn)[j]; }
}

__device__ __forceinline__ void hsrc(int code, const void* outv, const void* hiddens,
                                     const void* initc, const void** hb, size_t* ho){
  if (code & 0x40000000){ *hb = hiddens; *ho = (size_t)(code & 0x0FFFFFFF)*DIM; }
  else if (code & 0x20000000){ *hb = initc; *ho = (size_t)(code & 0x0FFFFFFF)*DIM; }
  else { *hb = outv; *ho = (size_t)NB*DIM + (size_t)code*DIM; }
}

// ===========================================================================
// x-projection body: Xp[16384][3072] = cvt(ins @ Wi). 128x128 tiles, BK=64,
// counted-vmcnt pipeline. B pinned per XCD (tn trio), A streams.
// ===========================================================================
template<int ISF>
__device__ __forceinline__ void xproj_run(
    const void* __restrict__ ins, const u16* __restrict__ WiT,
    u16* __restrict__ xp, u16 (*As)[128*64], u16 (*Bs)[128*64])
{
  int tid=threadIdx.x, wave=tid>>6, lane=tid&63, quad=lane>>4, l16=lane&15;
  int wm=wave&1, wn=wave>>1;
  int srow = wave*8 + (lane>>3), c8=(lane&7)*8;
  int swzc = c8 ^ ((srow&7)<<3);
  int rsw = (l16&7)<<3;
  int idx = blockIdx.x >> 3;
  int tn = (blockIdx.x & 7)*3 + (idx % 3);
  int tm = idx / 3;
  f32x4 acc[4][4] = {};
  unsigned aoff[4], boff[4];
  #pragma unroll
  for (int p=0;p<4;++p){
    aoff[p] = (unsigned)(tm*128 + p*32 + srow)*DIM + c8;
    boff[p] = (unsigned)(tn*128 + p*32 + srow)*DIM + swzc;
  }
  // prologue: B[0]+A[0] staged, A[64] prefetch issued, counted barrier.
  #pragma unroll
  for (int p=0;p<4;++p) gl_lds16(WiT + boff[p], &Bs[0][(p*32+wave*8)*64], lane);
  #pragma unroll
  for (int p=0;p<4;++p) stage16(ins, aoff[p], ISF, &As[0][(p*32+srow)*64 + swzc]);
  f32x4 ra0[4], ra1[4];
  #pragma unroll
  for (int p=0;p<4;++p){
    if constexpr (ISF){ const float* f=(const float*)ins + aoff[p] + 64;
      ra0[p]=*(const f32x4*)f; ra1[p]=*(const f32x4*)(f+4); }
    else ra0[p]=*(const f32x4*)((const u16*)ins + aoff[p] + 64);
  }
  if constexpr (ISF) BAR_N(8); else BAR_N(4);
  int cur = 0;
  #pragma unroll 1
  for (int ko=64; ko<1024; ko+=64){
    int nxt = cur^1;
    #pragma unroll
    for (int p=0;p<4;++p) gl_lds16(WiT + boff[p] + ko, &Bs[nxt][(p*32+wave*8)*64], lane);
    #pragma unroll
    for (int kk=0;kk<64;kk+=32){
      int rc = (kk + quad*8) ^ rsw;
      bf16x8 af[4], bfv[4];
      #pragma unroll
      for (int mi=0;mi<4;++mi) af[mi]  = *(const bf16x8*)&As[cur][(wm*64+mi*16+l16)*64 + rc];
      #pragma unroll
      for (int ni=0;ni<4;++ni) bfv[ni] = *(const bf16x8*)&Bs[cur][(wn*64+ni*16+l16)*64 + rc];
      #pragma unroll
      for (int mi=0;mi<4;++mi)
        #pragma unroll
        for (int ni=0;ni<4;++ni)
          acc[mi][ni] = __builtin_amdgcn_mfma_f32_16x16x32_bf16(af[mi],bfv[ni],acc[mi][ni],0,0,0);
    }
    #pragma unroll
    for (int p=0;p<4;++p){
      uint4 w;
      if constexpr (ISF){ w.x=pk2(ra0[p][0],ra0[p][1]); w.y=pk2(ra0[p][2],ra0[p][3]);
                w.z=pk2(ra1[p][0],ra1[p][1]); w.w=pk2(ra1[p][2],ra1[p][3]); }
      else { union{f32x4 f; uint4 u;} cv; cv.f=ra0[p]; w=cv.u; }
      *(uint4*)&As[nxt][(p*32+srow)*64 + swzc] = w;
    }
    if (ko < 960){
      #pragma unroll
      for (int p=0;p<4;++p){
        if constexpr (ISF){ const float* f=(const float*)ins + aoff[p] + ko + 64;
          ra0[p]=*(const f32x4*)f; ra1[p]=*(const f32x4*)(f+4); }
        else ra0[p]=*(const f32x4*)((const u16*)ins + aoff[p] + ko + 64);
      }
      if constexpr (ISF) BAR_N(8); else BAR_N(4);
    } else {
      BAR_N(0);
    }
    cur = nxt;
  }
  // tail compute on As[cur]/Bs[cur] = K-step 960.
  #pragma unroll
  for (int kk=0;kk<64;kk+=32){
    int rc = (kk + quad*8) ^ rsw;
    bf16x8 af[4], bfv[4];
    #pragma unroll
    for (int mi=0;mi<4;++mi) af[mi]  = *(const bf16x8*)&As[cur][(wm*64+mi*16+l16)*64 + rc];
    #pragma unroll
    for (int ni=0;ni<4;++ni) bfv[ni] = *(const bf16x8*)&Bs[cur][(wn*64+ni*16+l16)*64 + rc];
    #pragma unroll
    for (int mi=0;mi<4;++mi)
      #pragma unroll
      for (int ni=0;ni<4;++ni)
        acc[mi][ni] = __builtin_amdgcn_mfma_f32_16x16x32_bf16(af[mi],bfv[ni],acc[mi][ni],0,0,0);
  }
  #pragma unroll
  for (int mi=0;mi<4;++mi){
    int row = tm*128 + wm*64 + mi*16 + quad*4;
    #pragma unroll
    for (int ni=0;ni<4;++ni){
      int colB = tn*128 + wn*64 + ni*16 + l16;
      u16* op = xp + (size_t)row*3072 + colB;
      #pragma unroll
      for (int j=0;j<4;++j)
        op[(size_t)j*3072] = f2b(acc[mi][ni][j]);
    }
  }
}

__global__ __launch_bounds__(256, 2) void k_xproj(
    const void* __restrict__ ins, const u16* __restrict__ WiT,
    const int* __restrict__ dflag, u16* __restrict__ xp)
{
  __shared__ u16 As[2][128*64];
  __shared__ u16 Bs[2][128*64];
  if (dflag[3]) xproj_run<1>(ins, WiT, xp, As, Bs);
  else          xproj_run<0>(ins, WiT, xp, As, Bs);
}

// ===========================================================================
// fat phase body: 128 rows x 64 d-cols (192 gate rows), counted-vmcnt dbuf.
// ===========================================================================
#define FAT_MFMA(BUF, NGRP)                                                    \
        _Pragma("unroll")                                                      \
        for (int kk=0;kk<64;kk+=32){                                           \
          int rc = (kk + quad*8) ^ rsw;                                        \
          bf16x8 af[4];                                                        \
          _Pragma("unroll")                                                    \
          for (int mi=0;mi<4;++mi)                                             \
            af[mi] = *(const bf16x8*)&As[BUF][(wm*64+mi*16+l16)*64 + rc];      \
          _Pragma("unroll")                                                    \
          for (int g=0;g<3;++g){                                               \
            int grp = (g==2) ? (NGRP) : g;                                     \
            _Pragma("unroll")                                                  \
            for (int ni=0;ni<2;++ni){                                          \
              bf16x8 bfr = *(const bf16x8*)&Bs[BUF][(g*64+wn*32+ni*16+l16)*64 + rc]; \
              _Pragma("unroll")                                                \
              for (int mi=0;mi<4;++mi)                                         \
                acc[grp][mi][ni] = __builtin_amdgcn_mfma_f32_16x16x32_bf16(af[mi],bfr,acc[grp][mi][ni],0,0,0); \
            }                                                                  \
          }                                                                    \
        }

#define FAT_LOADA(BASEARR, OFFARR, KO)                                         \
      _Pragma("unroll")                                                        \
      for (int p=0;p<4;++p){                                                   \
        if constexpr (ISF){ const float* f_=(const float*)BASEARR[p]+OFFARR[p]+(KO); \
          ra0[p]=*(const f32x4*)f_; ra1[p]=*(const f32x4*)(f_+4); }            \
        else ra0[p]=*(const f32x4*)((const u16*)BASEARR[p]+OFFARR[p]+(KO));    \
      }

#define FAT_WRA(NXT)                                                           \
      _Pragma("unroll")                                                        \
      for (int p=0;p<4;++p){                                                   \
        uint4 w_;                                                              \
        if constexpr (ISF){ w_.x=pk2(ra0[p][0],ra0[p][1]); w_.y=pk2(ra0[p][2],ra0[p][3]); \
                  w_.z=pk2(ra1[p][0],ra1[p][1]); w_.w=pk2(ra1[p][2],ra1[p][3]);}\
        else { union{f32x4 f; uint4 u;} cv_; cv_.f=ra0[p]; w_=cv_.u; }         \
        *(uint4*)&As[NXT][(p*32+srow)*64 + swzc] = w_;                         \
      }

#define FAT_PANEL(BASEARR, OFFARR, WTP, NGRP)                                  \
    {                                                                          \
      __syncthreads();                                                         \
      _Pragma("unroll")                                                        \
      for (int p=0;p<6;++p)                                                    \
        gl_lds16(WTP + boffB[p], &Bs[0][(p*32+wave*8)*64], lane);              \
      _Pragma("unroll")                                                        \
      for (int p=0;p<4;++p)                                                    \
        stage16(BASEARR[p], OFFARR[p], ISF, &As[0][(p*32+srow)*64 + swzc]);    \
      f32x4 ra0[4], ra1[4];                                                    \
      FAT_LOADA(BASEARR, OFFARR, 64)                                           \
      if constexpr (ISF) BAR_N(8); else BAR_N(4);                              \
      int cur = 0;                                                             \
      _Pragma("unroll 1")                                                      \
      for (int ko=64; ko<1024; ko+=64){                                        \
        int nxt = cur^1;                                                       \
        _Pragma("unroll")                                                      \
        for (int p=0;p<6;++p)                                                  \
          gl_lds16(WTP + boffB[p] + ko, &Bs[nxt][(p*32+wave*8)*64], lane);     \
        FAT_MFMA(cur, NGRP)                                                    \
        FAT_WRA(nxt)                                                           \
        if (ko < 960){                                                         \
          FAT_LOADA(BASEARR, OFFARR, ko+64)                                    \
          if constexpr (ISF) BAR_N(8); else BAR_N(4);                          \
        } else {                                                               \
          BAR_N(0);                                                            \
        }                                                                      \
        cur = nxt;                                                             \
      }                                                                        \
      FAT_MFMA(cur, NGRP)                                                      \
    }

template<bool HOIST, int ISF>
__device__ __forceinline__ void fat_run(
    int count, int base, int ntot,
    const int* __restrict__ row_tb, const int* __restrict__ row_src,
    const void* __restrict__ ins, const void* __restrict__ hiddens,
    const void* __restrict__ initc, const u16* __restrict__ WiT,
    const u16* __restrict__ WhT, const u16* __restrict__ bi_b,
    const u16* __restrict__ bhn_b, const u16* __restrict__ xp,
    void* __restrict__ outv, u16 (*As)[128*64], u16 (*Bs)[192*64])
{
  constexpr int NG = HOIST ? 3 : 4;
  int tid=threadIdx.x, wave=tid>>6, lane=tid&63, quad=lane>>4, l16=lane&15;
  int wm=wave&1, wn=wave>>1;
  int srow = wave*8 + (lane>>3), c8=(lane&7)*8;
  int swzc = c8 ^ ((srow&7)<<3);
  int rsw = (l16&7)<<3;

  for (int raw = blockIdx.x; raw < ntot; raw += gridDim.x){
    // dblk-pinned XCD map: XCD (raw&7) owns dblk pair {2x,2x+1}.
    int idx2 = raw >> 3;
    int dblk = ((raw & 7) << 1) | (idx2 & 1);
    int tm = idx2 >> 1;
    int d0 = dblk*64;
    unsigned xoff[4], hoff[4];
    const void* hbv[4];
    const void* xbv[4];
    #pragma unroll
    for (int p=0;p<4;++p){
      int lr = tm*128 + p*32 + srow;
      int idx = base + ((lr < count) ? lr : 0);
      int tb = row_tb[idx], code = row_src[idx];
      xoff[p] = (unsigned)tb*DIM + c8;
      xbv[p] = ins;
      size_t ho; const void* hb;
      hsrc(code, outv, hiddens, initc, &hb, &ho);
      hbv[p] = hb; hoff[p] = (unsigned)ho + c8;
    }
    int boffB[6];
    #pragma unroll
    for (int p=0;p<6;++p)
      boffB[p] = ((p>>1)*DIM + d0 + (p&1)*32 + srow)*DIM + swzc;
    f32x4 acc[NG][4][2] = {};

    if constexpr (!HOIST){
      FAT_PANEL(xbv, xoff, WiT, 2)
    }
    FAT_PANEL(hbv, hoff, WhT, (NG-1))

    // ---- fused GRU epilogue ----
    int col0 = d0 + wn*32;
    float brv[2], bzv[2], bnv[2], bhv[2];
    #pragma unroll
    for (int ni=0;ni<2;++ni){
      int c = col0 + ni*16 + l16;
      brv[ni]=b2f(bi_b[c]); bzv[ni]=b2f(bi_b[1024+c]);
      bnv[ni]=b2f(bi_b[2048+c]); bhv[ni]=b2f(bhn_b[c]);
    }
    #pragma unroll
    for (int mi=0;mi<4;++mi){
      int lrow0 = tm*128 + wm*64 + mi*16 + quad*4;
      #pragma unroll
      for (int j=0;j<4;++j){
        int lrow = lrow0 + j;
        if (lrow >= count) continue;
        int idx = base + lrow;
        int tb = row_tb[idx], code = row_src[idx];
        size_t ho; const void* hb;
        hsrc(code, outv, hiddens, initc, &hb, &ho);
        #pragma unroll
        for (int ni=0;ni<2;++ni){
          int c = col0 + ni*16 + l16;
          float hpv = ISF ? ((const float*)hb)[ho + c] : b2f(((const u16*)hb)[ho + c]);
          float xr = 0.f, xz = 0.f, xn = 0.f;
          if constexpr (HOIST){
            const u16* xrow = xp + (size_t)tb*3072 + c;
            xr = b2f(xrow[0]); xz = b2f(xrow[1024]); xn = b2f(xrow[2048]);
          }
          float r = sigf(brv[ni] + xr + acc[0][mi][ni][j]);
          float z = sigf(bzv[ni] + xz + acc[1][mi][ni][j]);
          float nx = HOIST ? xn : acc[2][mi][ni][j];
          float n = tanh_f(bnv[ni] + nx + r*(acc[NG-1][mi][ni][j] + bhv[ni]));
          float hnew = (1.0f - z)*n + z*hpv;
          size_t yo = (size_t)NB*DIM + (size_t)tb*DIM + c;
          if (ISF) ((float*)outv)[yo] = hnew;
          else     ((u16*)outv)[yo] = f2b(hnew);
        }
      }
    }
  }
}

template<bool HOIST>
__global__ __launch_bounds__(256, 2) void phase_fat(
    int s, const int* __restrict__ pcnt, const int* __restrict__ pbase,
    const int* __restrict__ row_tb, const int* __restrict__ row_src,
    const void* __restrict__ ins, const void* __restrict__ hiddens,
    const void* __restrict__ initc, const u16* __restrict__ WiT,
    const u16* __restrict__ WhT, const u16* __restrict__ bi_b,
    const u16* __restrict__ bhn_b, const int* __restrict__ dflag,
    const u16* __restrict__ xp, void* __restrict__ outv)
{
  int count = pcnt[s];
  if (count <= 0) return;
  int base = pbase[s];
  int mtiles = (count + 127) >> 7;
  int ntot = mtiles << 4;
  __shared__ u16 As[2][128*64];
  __shared__ u16 Bs[2][192*64];
  if (dflag[3]) fat_run<HOIST,1>(count, base, ntot, row_tb, row_src, ins, hiddens,
                                 initc, WiT, WhT, bi_b, bhn_b, xp, outv, As, Bs);
  else          fat_run<HOIST,0>(count, base, ntot, row_tb, row_src, ins, hiddens,
                                 initc, WiT, WhT, bi_b, bhn_b, xp, outv, As, Bs);
}

// ===========================================================================
// thin phase body: 64 rows x 16 d-cols (48 gate rows), counted-vmcnt dbuf.
// ===========================================================================
#define THIN_MFMA(BUF, NGRP)                                                   \
      _Pragma("unroll")                                                        \
      for (int kk=0;kk<64;kk+=32){                                             \
        int rc = (kk + quad*8) ^ rsw;                                          \
        bf16x8 af = *(const bf16x8*)&As[BUF][(wave*16+l16)*64 + rc];           \
        _Pragma("unroll")                                                      \
        for (int g=0;g<3;++g){                                                 \
          bf16x8 bfr = *(const bf16x8*)&Bs[BUF][(g*16+l16)*64 + rc];           \
          int grp = (g==2) ? (NGRP) : g;                                       \
          acc[grp] = __builtin_amdgcn_mfma_f32_16x16x32_bf16(af,bfr,acc[grp],0,0,0); \
        }                                                                      \
      }

#define THIN_LOADA(BASEARR, OFFARR, KO)                                        \
      _Pragma("unroll")                                                        \
      for (int p=0;p<2;++p){                                                   \
        if constexpr (ISF){ const float* f_=(const float*)BASEARR[p]+OFFARR[p]+(KO); \
          ra0[p]=*(const f32x4*)f_; ra1[p]=*(const f32x4*)(f_+4); }            \
        else ra0[p]=*(const f32x4*)((const u16*)BASEARR[p]+OFFARR[p]+(KO));    \
      }

#define THIN_WRA(NXT)                                                          \
      _Pragma("unroll")                                                        \
      for (int p=0;p<2;++p){                                                   \
        uint4 w_;                                                              \
        if constexpr (ISF){ w_.x=pk2(ra0[p][0],ra0[p][1]); w_.y=pk2(ra0[p][2],ra0[p][3]); \
                  w_.z=pk2(ra1[p][0],ra1[p][1]); w_.w=pk2(ra1[p][2],ra1[p][3]);}\
        else { union{f32x4 f; uint4 u;} cv_; cv_.f=ra0[p]; w_=cv_.u; }         \
        *(uint4*)&As[NXT][(p*32+srow)*64 + swzc] = w_;                         \
      }

#define THIN_PANEL(BASEARR, OFFARR, WTP, NGRP)                                 \
    {                                                                          \
      __syncthreads();                                                         \
      gl_lds16(WTP + boffA, &Bs[0][(wave*8)*64], lane);                        \
      if (wave < 2) gl_lds16(WTP + boffC, &Bs[0][(32+wave*8)*64], lane);       \
      stage16(BASEARR[0], OFFARR[0], ISF, &As[0][srow*64 + swzc]);             \
      stage16(BASEARR[1], OFFARR[1], ISF, &As[0][(32+srow)*64 + swzc]);        \
      f32x4 ra0[2], ra1[2];                                                    \
      THIN_LOADA(BASEARR, OFFARR, 64)                                          \
      if constexpr (ISF) BAR_N(4); else BAR_N(2);                              \
      int cur = 0;                                                             \
      _Pragma("unroll 1")                                                      \
      for (int ko=64; ko<1024; ko+=64){                                        \
        int nxt = cur^1;                                                       \
        gl_lds16(WTP + boffA + ko, &Bs[nxt][(wave*8)*64], lane);               \
        if (wave < 2) gl_lds16(WTP + boffC + ko, &Bs[nxt][(32+wave*8)*64], lane); \
        THIN_MFMA(cur, NGRP)                                                   \
        THIN_WRA(nxt)                                                          \
        if (ko < 960){                                                         \
          THIN_LOADA(BASEARR, OFFARR, ko+64)                                   \
          if constexpr (ISF) BAR_N(4); else BAR_N(2);                          \
        } else {                                                               \
          BAR_N(0);                                                            \
        }                                                                      \
        cur = nxt;                                                             \
      }                                                                        \
      THIN_MFMA(cur, NGRP)                                                     \
    }

template<bool HOIST, int ISF>
__device__ __forceinline__ void thin_run(
    int count, int base, int ntot,
    const int* __restrict__ row_tb, const int* __restrict__ row_src,
    const void* __restrict__ ins, const void* __restrict__ hiddens,
    const void* __restrict__ initc, const u16* __restrict__ WiT,
    const u16* __restrict__ WhT, const u16* __restrict__ bi_b,
    const u16* __restrict__ bhn_b, const u16* __restrict__ xp,
    void* __restrict__ outv, u16 (*As)[64*64], u16 (*Bs)[48*64])
{
  constexpr int NG = HOIST ? 3 : 4;
  int tid=threadIdx.x, wave=tid>>6, lane=tid&63, quad=lane>>4, l16=lane&15;
  int srow = wave*8 + (lane>>3), c8=(lane&7)*8;
  int swzc = c8 ^ ((srow&7)<<3);
  int rsw = (l16&7)<<3;

  for (int tile = blockIdx.x; tile < ntot; tile += gridDim.x){
    int tm = tile >> 6, dblk = tile & 63, d0 = dblk*16;
    unsigned xoff[2], hoff[2];
    const void* hbv[2];
    const void* xbv[2];
    #pragma unroll
    for (int p=0;p<2;++p){
      int lr = tm*64 + p*32 + srow;
      int idx = base + ((lr < count) ? lr : 0);
      int tb = row_tb[idx], code = row_src[idx];
      xoff[p] = (unsigned)tb*DIM + c8;
      xbv[p] = ins;
      size_t ho; const void* hb;
      hsrc(code, outv, hiddens, initc, &hb, &ho);
      hbv[p] = hb; hoff[p] = (unsigned)ho + c8;
    }
    int boffA = ((srow>>4)*DIM + d0 + (srow&15))*DIM + swzc;   // gates 0,1
    int boffC = (2*DIM + d0 + srow)*DIM + swzc;                // gate 2 (wave<2)
    f32x4 acc[NG] = {};

    if constexpr (!HOIST){
      THIN_PANEL(xbv, xoff, WiT, 2)
    }
    THIN_PANEL(hbv, hoff, WhT, (HOIST ? 2 : 3))

    int col = d0 + l16;
    float br = b2f(bi_b[col]), bz = b2f(bi_b[1024+col]);
    float bn = b2f(bi_b[2048+col]), bh = b2f(bhn_b[col]);
    int lrow0 = tm*64 + wave*16 + quad*4;
    #pragma unroll
    for (int j=0;j<4;++j){
      int lrow = lrow0 + j;
      if (lrow >= count) continue;
      int idx = base + lrow;
      int tb = row_tb[idx], code = row_src[idx];
      size_t ho; const void* hb;
      hsrc(code, outv, hiddens, initc, &hb, &ho);
      float hpv = ISF ? ((const float*)hb)[ho + col] : b2f(((const u16*)hb)[ho + col]);
      float xr = 0.f, xz = 0.f, xn = 0.f;
      if constexpr (HOIST){
        const u16* xrow = xp + (size_t)tb*3072 + col;
        xr = b2f(xrow[0]); xz = b2f(xrow[1024]); xn = b2f(xrow[2048]);
      }
      float r = sigf(br + xr + acc[0][j]);
      float z = sigf(bz + xz + acc[1][j]);
      float nx = HOIST ? xn : acc[2][j];
      float n = tanh_f(bn + nx + r*(acc[NG-1][j] + bh));
      float hnew = (1.0f - z)*n + z*hpv;
      size_t yo = (size_t)NB*DIM + (size_t)tb*DIM + col;
      if (ISF) ((float*)outv)[yo] = hnew;
      else     ((u16*)outv)[yo] = f2b(hnew);
    }
  }
}

template<bool HOIST>
__global__ __launch_bounds__(256, 4) void phase_thin(
    int s, const int* __restrict__ pcnt, const int* __restrict__ pbase,
    const int* __restrict__ row_tb, const int* __restrict__ row_src,
    const void* __restrict__ ins, const void* __restrict__ hiddens,
    const void* __restrict__ initc, const u16* __restrict__ WiT,
    const u16* __restrict__ WhT, const u16* __restrict__ bi_b,
    const u16* __restrict__ bhn_b, const int* __restrict__ dflag,
    const u16* __restrict__ xp, void* __restrict__ outv)
{
  int count = pcnt[s];
  if (count <= 0) return;
  int base = pbase[s];
  int mtiles = (count + 63) >> 6;
  int ntot = mtiles << 6;
  __shared__ u16 As[2][64*64];
  __shared__ u16 Bs[2][48*64];
  if (dflag[3]) thin_run<HOIST,1>(count, base, ntot, row_tb, row_src, ins, hiddens,
                                  initc, WiT, WhT, bi_b, bhn_b, xp, outv, As, Bs);
  else          thin_run<HOIST,0>(count, base, ntot, row_tb, row_src, ins, hiddens,
                                  initc, WiT, WhT, bi_b, bhn_b, xp, outv, As, Bs);
}

__global__ void k_final(const int* dflag, void* out){
  int isf = dflag[3];
  size_t i = (size_t)(blockIdx.x*256 + threadIdx.x)*4;
  size_t src = (size_t)NB*DIM + (size_t)(T_STEPS-1)*NB*DIM;
  if (isf){
    float* o = (float*)out;
    *(f32x4*)(o + i) = *(const f32x4*)(o + src + i);
  } else {
    u16* o = (u16*)out;
    *(uint2*)(o + i) = *(const uint2*)(o + src + i);
  }
}

extern "C" void kernel_launch(void* const* d_in, const int* in_sizes, int n_in,
                              void* d_out, int out_size, void* d_ws, size_t ws_size,
                              hipStream_t stream){
  const void* ins = d_in[0];
  const void* hid = d_in[1];
  const void* dn  = d_in[2];
  const void* ini = d_in[3];
  const void* Wi  = d_in[4];
  const void* Wh  = d_in[5];
  const void* bi  = d_in[6];
  const void* bhn = d_in[7];

  char* ws = (char*)d_ws;
  int* dflag  = (int*)(ws + 0);
  int* cnt    = (int*)(ws + 256);
  int* basep  = (int*)(ws + 512);
  int* cur    = (int*)(ws + 1024);
  int* s_of   = (int*)(ws + 4096);          // 64 KB
  int* row_tb = (int*)(ws + 69632);         // 64 KB
  int* row_src= (int*)(ws + 135168);        // 64 KB
  u16* bi_b   = (u16*)(ws + 200704);        // 6 KB
  u16* bhn_b  = (u16*)(ws + 208896);        // 2 KB
  u16* WiT    = (u16*)(ws + 262144);        // 6 MB
  u16* WhT    = (u16*)(ws + 6553600);       // 6 MB (end 12845056)
  u16* xp     = (u16*)(ws + 12845056);      // 96 MB bf16 Xp (if ws allows)

  const int hoist = (ws_size >= 113508352ull) ? 1 : 0;

  k_setup0<<<1,256,0,stream>>>(dn, ins, cnt, cur, dflag);
  k_assign<<<NB,T_STEPS,0,stream>>>(dn, dflag, s_of, cnt);
  k_scan<<<1,64,0,stream>>>(cnt, basep, cur);
  k_fill<<<NPH,256,0,stream>>>(dn, dflag, s_of, basep, row_tb, row_src);
  k_transpose<<<dim3(16,48),256,0,stream>>>(Wi, WiT, dflag);
  k_transpose<<<dim3(16,48),256,0,stream>>>(Wh, WhT, dflag);
  k_bias<<<16,256,0,stream>>>(bi, bhn, dflag, bi_b, bhn_b);

  if (hoist){
    k_xproj<<<3072,256,0,stream>>>(ins, WiT, dflag, xp);
    for (int s=0;s<6;++s)
      phase_fat<true><<<1024,256,0,stream>>>(s, cnt, basep, row_tb, row_src, ins, hid, ini,
                                             WiT, WhT, bi_b, bhn_b, dflag, xp, d_out);
    for (int s=6;s<NPH;++s)
      phase_thin<true><<<256,256,0,stream>>>(s, cnt, basep, row_tb, row_src, ins, hid, ini,
                                             WiT, WhT, bi_b, bhn_b, dflag, xp, d_out);
  } else {
    for (int s=0;s<6;++s)
      phase_fat<false><<<1024,256,0,stream>>>(s, cnt, basep, row_tb, row_src, ins, hid, ini,
                                              WiT, WhT, bi_b, bhn_b, dflag, xp, d_out);
    for (int s=6;s<NPH;++s)
      phase_thin<false><<<256,256,0,stream>>>(s, cnt, basep, row_tb, row_src, ins, hid, ini,
                                              WiT, WhT, bi_b, bhn_b, dflag, xp, d_out);
  }
  k_final<<<64,256,0,stream>>>(dflag, d_out);
}